// Round 9
// baseline (423.024 us; speedup 1.0000x reference)
//
#include <hip/hip_runtime.h>

typedef unsigned short u16;
typedef __attribute__((ext_vector_type(8))) short s8v;
typedef __attribute__((ext_vector_type(8))) __bf16 bf8;
typedef __attribute__((ext_vector_type(4))) float f4v;

#define GLB(p) ((const __attribute__((address_space(1))) void*)(p))
#define LDS(p) ((__attribute__((address_space(3))) void*)(p))

static __device__ __forceinline__ float b2f(u16 u) {
    union { unsigned int i; float f; } v; v.i = ((unsigned int)u) << 16; return v.f;
}
static __device__ __forceinline__ u16 f2b(float f) {
    union { float f; unsigned int i; } v; v.f = f;
    v.i += 0x7fffu + ((v.i >> 16) & 1u);   // RNE
    return (u16)(v.i >> 16);
}

// ---------------- fused f32 -> bf16 convert (X, W_qkv, W_o) ----------------
__global__ __launch_bounds__(256) void k_conv(const float* __restrict__ X,
                                              const float* __restrict__ Wq,
                                              const float* __restrict__ Wo,
                                              u16* __restrict__ Xb,
                                              u16* __restrict__ Wqb,
                                              u16* __restrict__ Wob) {
    int i = blockIdx.x * 256 + threadIdx.x;      // 8388608 quads total
    const float* in; u16* out; int off;
    if (i < 4194304)      { in = X;  out = Xb;  off = i; }
    else if (i < 7340032) { in = Wq; out = Wqb; off = i - 4194304; }
    else                  { in = Wo; out = Wob; off = i - 7340032; }
    float4 v = ((const float4*)in)[off];
    union { u16 u[4]; unsigned long long ll; } o;
    o.u[0] = f2b(v.x); o.u[1] = f2b(v.y); o.u[2] = f2b(v.z); o.u[3] = f2b(v.w);
    ((unsigned long long*)out)[off] = o.ll;
}

// ====== C = A(MxK) * B(NxK)^T, 256xBN tile, BK=32, 8 waves, 2 blocks/CU ======
// Single phase per K-tile: {vmcnt(0) on 1-iter-old stage | bar | stage-next |
// 12 ds_reads | 32 MFMA}. TLP (2 blocks/CU) covers the barrier/LDS windows.
// LDS rows are 128B PAIR-PACKED: LDS row r holds global rows (r, r+HALF)'s 32-k
// slices; slot = (g + 4h) ^ (r&7). Every aligned 8-lane group of a b128 read
// hits 8 distinct 16B slots -> conflict-free. Inverse swizzle on staging src.
// MODE 0 (BN=256): padded-LDS-transpose epilogue (2 passes of 128 rows) ->
//   Q/K [bh][t][128] with FUSED ROPE, V transposed [bh][128][t].
// MODE 1 (BN=128): f32 row-major C.
template<int MODE>
__global__ __launch_bounds__(512, 2) void k_gemm_bt(
    const u16* __restrict__ A, const u16* __restrict__ B,
    int K, int N, int gx,
    u16* __restrict__ Qb, u16* __restrict__ Kb, u16* __restrict__ Vt,
    float* __restrict__ Cf, const int* __restrict__ pos)
{
    constexpr int BN   = MODE ? 128 : 256;
    constexpr int NB   = MODE ? 2 : 4;           // B-frags per wave
    constexpr int BUFS = MODE ? 12288 : 16384;   // u16 per K-tile buf
    extern __shared__ __align__(16) u16 Ls[];

    const int t    = threadIdx.x;
    const int lane = t & 63;
    const int wid  = t >> 6;
    const int wm = wid >> 2, wn = wid & 3;       // 2x4 wave grid
    const int la = lane & 15, lb = lane >> 4;

    // XCD-bijective block swizzle (grid % 8 == 0)
    const int bid = (int)blockIdx.x;
    const int id2 = (bid & 7) * ((int)gridDim.x >> 3) + (bid >> 3);
    const int bx = id2 % gx, by = id2 / gx;
    const long arow0 = (long)by * 256;
    const long brow0 = (long)bx * BN;

    // ---- staging geometry: linear LDS dest, inverse-swizzled global src ----
    const int r0 = t >> 3, sl = t & 7;           // LDS row (0..63), slot
    const int sA0 = sl ^ (r0 & 7);
    const int sA1 = sl ^ ((r0 + 64) & 7);
    const long RA0 = r0 + 128 * (sA0 >> 2);      // A pairs (r, r+128)
    const long RA1 = 64 + r0 + 128 * (sA1 >> 2);
    const u16* As0 = A + (arow0 + RA0) * (long)K + (sA0 & 3) * 8;
    const u16* As1 = A + (arow0 + RA1) * (long)K + (sA1 & 3) * 8;
    const u16 *Bsrc0, *Bsrc1;
    if (MODE == 0) {                             // B pairs (r, r+128), 2 insts
        Bsrc0 = B + (brow0 + RA0) * (long)K + (sA0 & 3) * 8;
        Bsrc1 = B + (brow0 + RA1) * (long)K + (sA1 & 3) * 8;
    } else {                                     // B pairs (r, r+64), 1 inst
        const long RB0 = r0 + 64 * (sA0 >> 2);
        Bsrc0 = B + (brow0 + RB0) * (long)K + (sA0 & 3) * 8;
        Bsrc1 = nullptr;
    }

#define STG(q_, kt_) do {                                                        \
        const long ko_ = (long)(kt_) * 32;                                       \
        u16* d_ = Ls + (q_) * BUFS + t * 8;                                      \
        __builtin_amdgcn_global_load_lds(GLB(As0 + ko_),   LDS(d_),         16, 0, 0); \
        __builtin_amdgcn_global_load_lds(GLB(As1 + ko_),   LDS(d_ + 4096),  16, 0, 0); \
        __builtin_amdgcn_global_load_lds(GLB(Bsrc0 + ko_), LDS(d_ + 8192),  16, 0, 0); \
        if (MODE == 0)                                                           \
            __builtin_amdgcn_global_load_lds(GLB(Bsrc1 + ko_), LDS(d_ + 12288), 16, 0, 0); \
    } while (0)
#define RD(off) (*(const bf8*)(Ls + (off)))

    f4v acc[8][NB];
#pragma unroll
    for (int m = 0; m < 8; m++)
#pragma unroll
        for (int n = 0; n < NB; n++) acc[m][n] = (f4v){0.f, 0.f, 0.f, 0.f};

    // fragment-read offsets (u16): row (R&127)*64, slot ((lb+4h)^(la&7))*8
    const int aOff = la * 64 + ((lb + 4 * wm) ^ (la & 7)) * 8;                 // + mi*1024
    int bOff[NB];
#pragma unroll
    for (int ni = 0; ni < NB; ni++) {
        if (MODE == 0) {
            bOff[ni] = 8192 + (wn & 1) * 4096 + ni * 1024 + la * 64
                     + ((lb + 4 * (wn >> 1)) ^ (la & 7)) * 8;
        } else {
            const int Rb = wn * 32 + ni * 16;    // + la (la<16, no crossing)
            bOff[ni] = 8192 + ((Rb & 63) + la) * 64
                     + ((lb + 4 * (Rb >> 6)) ^ (la & 7)) * 8;
        }
    }

    const int NKT = K >> 5;
    STG(0, 0);
    for (int X = 0; X < NKT; ++X) {
        asm volatile("s_waitcnt vmcnt(0)" ::: "memory");   // own stage(X) landed
        __builtin_amdgcn_s_barrier();                      // everyone's landed
        int S = X + 1; if (S > NKT - 1) S = NKT - 1;       // idempotent tail
        STG((X + 1) & 1, S);

        const int D = (X & 1) * BUFS;
        bf8 aF[8], bF[NB];
#pragma unroll
        for (int mi = 0; mi < 8; mi++) aF[mi] = RD(D + aOff + mi * 1024);
#pragma unroll
        for (int ni = 0; ni < NB; ni++) bF[ni] = RD(D + bOff[ni]);

        __builtin_amdgcn_s_setprio(1);
#pragma unroll
        for (int mi = 0; mi < 8; mi++)
#pragma unroll
            for (int ni = 0; ni < NB; ni++)
                acc[mi][ni] = __builtin_amdgcn_mfma_f32_16x16x32_bf16(aF[mi], bF[ni], acc[mi][ni], 0, 0, 0);
        __builtin_amdgcn_s_setprio(0);
    }
#undef STG
#undef RD

    if (MODE == 1) {
#pragma unroll
        for (int mi = 0; mi < 8; mi++)
#pragma unroll
            for (int ni = 0; ni < NB; ni++) {
                const long grow0 = arow0 + wm * 128 + mi * 16 + lb * 4;
                const int  gcol  = (int)brow0 + wn * 32 + ni * 16 + la;
#pragma unroll
                for (int i = 0; i < 4; i++)
                    Cf[(grow0 + i) * (long)N + gcol] = acc[mi][ni][i];
            }
        return;
    }

    // ---- MODE 0 epilogue: 2 passes of 128 rows through padded LDS ----
    __syncthreads();                 // drains vm/lgkm; reuse Ls
    const int part = (int)(brow0 >> 11);         // 0=Q 1=K 2=V
    const int h0   = ((int)brow0 & 2047) >> 7;   // first head (2 heads/tile)
    const int bidx = (int)(arow0 >> 11);
    const int t0   = (int)arow0 & 2047;

    if (part == 2) {
        // E[dl*132 + tl_loc], dl 0..255, tl_loc 0..127
#pragma unroll
        for (int p = 0; p < 2; p++) {
            if (wm == p) {
#pragma unroll
                for (int mi = 0; mi < 8; mi++)
#pragma unroll
                    for (int ni = 0; ni < 4; ni++) {
                        const int tlb = mi * 16 + lb * 4;
                        const int dl  = wn * 64 + ni * 16 + la;
#pragma unroll
                        for (int i2 = 0; i2 < 2; i2++) {
                            unsigned int pk = (unsigned int)f2b(acc[mi][ni][i2 * 2])
                                            | ((unsigned int)f2b(acc[mi][ni][i2 * 2 + 1]) << 16);
                            *(unsigned int*)(Ls + dl * 132 + tlb + i2 * 2) = pk;
                        }
                    }
            }
            __syncthreads();
#pragma unroll
            for (int j = 0; j < 8; j++) {
                const int dl  = j * 32 + wid * 4 + (lane >> 4);
                const int tl8 = (lane & 15) * 8;
                bf8 v = *(const bf8*)(Ls + dl * 132 + tl8);
                const long bh = (long)(bidx * 16 + h0 + (dl >> 7));
                *(bf8*)(Vt + (bh << 18) + ((long)(dl & 127) << 11) + t0 + p * 128 + tl8) = v;
            }
            __syncthreads();
        }
    } else {
        u16* dst = (part == 0) ? Qb : Kb;
        const int c = t & 15;
        float invf[4];
#pragma unroll
        for (int p2 = 0; p2 < 4; p2++)
            invf[p2] = exp2f((float)(c * 4 + p2) * -0.20762050593046014f);
#pragma unroll
        for (int p = 0; p < 2; p++) {
            if (wm == p) {
#pragma unroll
                for (int mi = 0; mi < 8; mi++)
#pragma unroll
                    for (int ni = 0; ni < 4; ni++) {
                        const int tlb = mi * 16 + lb * 4;
                        const int dl  = wn * 64 + ni * 16 + la;
#pragma unroll
                        for (int i = 0; i < 4; i++)
                            Ls[(tlb + i) * 264 + dl] = f2b(acc[mi][ni][i]);
                    }
            }
            __syncthreads();
#pragma unroll
            for (int j = 0; j < 8; j++) {
                const int R  = j * 32 + (t >> 4);
                const int tl = R >> 1, hh = R & 1;
                s8v v = *(const s8v*)(Ls + tl * 264 + hh * 128 + c * 8);
                const int tg = t0 + p * 128 + tl;
                const float pf = (float)pos[tg];
                union { u16 u[8]; s8v v; } ov;
#pragma unroll
                for (int p2 = 0; p2 < 4; p2++) {
                    float x1 = b2f((u16)v[2 * p2]);
                    float x2 = b2f((u16)v[2 * p2 + 1]);
                    float sn, cs;
                    __sincosf(pf * invf[p2], &sn, &cs);
                    ov.u[2 * p2]     = f2b(x1 * cs - x2 * sn);
                    ov.u[2 * p2 + 1] = f2b(x1 * sn + x2 * cs);
                }
                const long bh = (long)(bidx * 16 + h0 + hh);
                *(s8v*)(dst + ((bh << 11) + tg) * 128 + c * 8) = ov.v;
            }
            __syncthreads();
        }
    }
}

// ---------------- causal flash attention, block-cooperative ----------------
__global__ __launch_bounds__(512) void k_attn(const u16* __restrict__ Qb,
                                              const u16* __restrict__ Kb,
                                              const u16* __restrict__ Vt,
                                              u16* __restrict__ Ob)
{
    __shared__ __align__(16) u16 Ks[2][32 * 128];
    __shared__ __align__(16) u16 Vs[2][64 * 64];
    __shared__ __align__(16) u16 Pl[8][32 * 32];

    const int tid  = threadIdx.x;
    const int lane = tid & 63;
    const int w    = tid >> 6;
    const int la = lane & 15, lb = lane >> 4;
    const int qg = 7 - ((int)blockIdx.x >> 6);
    const int bh = blockIdx.x & 63;
    const long base = (long)bh << 18;
    const int qt = qg * 8 + w;
    const int q0 = qt * 32;
    const int tiles_w = qt + 1;
    const int NT = qg * 8 + 8;
    const float scale = 0.08838834764831845f;

    bf8 qf[2][4];
#pragma unroll
    for (int m = 0; m < 2; m++)
#pragma unroll
        for (int kb = 0; kb < 4; kb++)
            qf[m][kb] = *(const bf8*)(Qb + base + (long)(q0 + m * 16 + la) * 128 + kb * 32 + lb * 8);

    f4v o[2][8];
#pragma unroll
    for (int m = 0; m < 2; m++)
#pragma unroll
        for (int n = 0; n < 8; n++) o[m][n] = (f4v){0.f, 0.f, 0.f, 0.f};
    float lst[2][4];
#pragma unroll
    for (int m = 0; m < 2; m++)
#pragma unroll
        for (int i = 0; i < 4; i++) lst[m][i] = 0.f;

    char* Pb = (char*)(Pl[w]);

    const int ko = tid * 16;
    const int kr = ko >> 8, kc = (ko & 255) ^ ((kr & 7) << 4);
    const int vo = tid * 16;
    const int vR = vo >> 7, vc = (vo & 127) ^ ((vR & 7) << 4);
    const int vd = 2 * vR + (vc >> 6), vt = (vc & 63) >> 1;

#define STAGE(buf, jt_) do {                                                        \
        const int kv0_ = (jt_) * 32;                                               \
        __builtin_amdgcn_global_load_lds(                                          \
            GLB(Kb + base + (long)(kv0_ + kr) * 128 + (kc >> 1)),                  \
            LDS((u16*)Ks[buf] + tid * 8), 16, 0, 0);                               \
        __builtin_amdgcn_global_load_lds(                                          \
            GLB(Vt + base + ((long)vd << 11) + kv0_ + vt),                         \
            LDS((u16*)Vs[buf] + tid * 8), 16, 0, 0);                               \
    } while (0)

    STAGE(0, 0);

    for (int jt = 0; jt < NT; ++jt) {
        const int buf = jt & 1;
        __syncthreads();
        if (jt + 1 < NT) STAGE(buf ^ 1, jt + 1);

        if (jt < tiles_w) {
            const char* KsB = (const char*)Ks[buf];
            const char* VsB = (const char*)Vs[buf];

            f4v s[2][2];
            s[0][0] = s[0][1] = s[1][0] = s[1][1] = (f4v){0.f, 0.f, 0.f, 0.f};
#pragma unroll
            for (int n = 0; n < 2; n++) {
                const int row = n * 16 + la;
#pragma unroll
                for (int kb = 0; kb < 4; kb++) {
                    bf8 kf = *(const bf8*)(KsB + row * 256 + ((kb * 64 + lb * 16) ^ ((row & 7) << 4)));
                    s[0][n] = __builtin_amdgcn_mfma_f32_16x16x32_bf16(qf[0][kb], kf, s[0][n], 0, 0, 0);
                    s[1][n] = __builtin_amdgcn_mfma_f32_16x16x32_bf16(qf[1][kb], kf, s[1][n], 0, 0, 0);
                }
            }

            bf8 vf[8];
#pragma unroll
            for (int nO = 0; nO < 8; nO++) {
                const int R = nO * 8 + (la >> 1);
                vf[nO] = *(const bf8*)(VsB + R * 128 + (((la & 1) * 64 + lb * 16) ^ ((R & 7) << 4)));
            }

            const bool diag = (jt == qt);
            float p[2][2][4];
#pragma unroll
            for (int m = 0; m < 2; m++)
#pragma unroll
                for (int n = 0; n < 2; n++)
#pragma unroll
                    for (int i = 0; i < 4; i++) {
                        float v = __expf(fmaf(s[m][n][i], scale, -8.0f));
                        if (diag && (n * 16 + la) > (m * 16 + lb * 4 + i)) v = 0.f;
                        p[m][n][i] = v;
                        lst[m][i] += v;
                    }

#pragma unroll
            for (int m = 0; m < 2; m++)
#pragma unroll
                for (int n = 0; n < 2; n++)
#pragma unroll
                    for (int i = 0; i < 4; i++) {
                        const int row = m * 16 + lb * 4 + i;
                        const int colb = (n * 16 + la) * 2;
                        *(u16*)(Pb + row * 64 + (colb ^ ((row & 3) << 4))) = f2b(p[m][n][i]);
                    }
            bf8 pa[2];
#pragma unroll
            for (int am = 0; am < 2; am++) {
                const int row = am * 16 + la;
                pa[am] = *(const bf8*)(Pb + row * 64 + ((lb * 16) ^ ((row & 3) << 4)));
            }
#pragma unroll
            for (int nO = 0; nO < 8; nO++) {
                o[0][nO] = __builtin_amdgcn_mfma_f32_16x16x32_bf16(pa[0], vf[nO], o[0][nO], 0, 0, 0);
                o[1][nO] = __builtin_amdgcn_mfma_f32_16x16x32_bf16(pa[1], vf[nO], o[1][nO], 0, 0, 0);
            }
        }
        __syncthreads();
    }
#undef STAGE

    float linv[2][4];
#pragma unroll
    for (int m = 0; m < 2; m++)
#pragma unroll
        for (int i = 0; i < 4; i++) {
            float l = lst[m][i];
            l += __shfl_xor(l, 1);
            l += __shfl_xor(l, 2);
            l += __shfl_xor(l, 4);
            l += __shfl_xor(l, 8);
            linv[m][i] = 1.0f / l;
        }

    const int b = bh >> 4, h = bh & 15;
#pragma unroll
    for (int m = 0; m < 2; m++)
#pragma unroll
        for (int nO = 0; nO < 8; nO++)
#pragma unroll
            for (int i = 0; i < 4; i++) {
                const int row = q0 + m * 16 + lb * 4 + i;
                const int d = nO * 16 + la;
                Ob[((long)(b * 2048 + row) << 11) + h * 128 + d] = f2b(o[m][nO][i] * linv[m][i]);
            }
}

extern "C" void kernel_launch(void* const* d_in, const int* in_sizes, int n_in,
                              void* d_out, int out_size, void* d_ws, size_t ws_size,
                              hipStream_t stream)
{
    const float* X    = (const float*)d_in[0];
    const int*   pos  = (const int*)d_in[1];
    const float* Wqkv = (const float*)d_in[2];
    const float* Wo   = (const float*)d_in[3];
    float* out = (float*)d_out;

    char* ws = (char*)d_ws;
    u16* Xb    = (u16*)(ws + 0);          // 8192x2048 bf16   (32 MiB)
    u16* Wqkvb = (u16*)(ws + 33554432);   // 6144x2048 bf16   (24 MiB)
    u16* Wob   = (u16*)(ws + 58720256);   // 2048x2048 bf16   ( 8 MiB)
    u16* Qb    = (u16*)(ws + 67108864);   // [bh][t][128] bf16 (32 MiB)
    u16* Kb    = (u16*)(ws + 100663296);  // [bh][t][128]
    u16* Vt    = (u16*)(ws + 134217728);  // [bh][128][t]  (transposed)
    u16* Ob    = (u16*)(ws + 167772160);  // [b][t][2048] bf16

    k_conv<<<32768, 256, 0, stream>>>(X, Wqkv, Wo, Xb, Wqkvb, Wob);
    // GEMM1: M=8192 N=6144 K=2048, BN=256 -> grid 24x32 = 768 blocks (RoPE fused)
    k_gemm_bt<0><<<768, 512, 67584, stream>>>(Xb, Wqkvb, 2048, 6144, 24, Qb, Kb, Vt, nullptr, pos);
    k_attn<<<512, 512, 0, stream>>>(Qb, Kb, Vt, Ob);
    // GEMM2: M=8192 N=2048 K=2048, BN=128 -> grid 16x32 = 512 blocks (2/CU)
    k_gemm_bt<1><<<512, 512, 49152, stream>>>(Ob, Wob, 2048, 2048, 16, nullptr, nullptr, nullptr, out, nullptr);
}

// Round 10
// 392.856 us; speedup vs baseline: 1.0768x; 1.0768x over previous
//
#include <hip/hip_runtime.h>

typedef unsigned short u16;
typedef __attribute__((ext_vector_type(8))) short s8v;
typedef __attribute__((ext_vector_type(8))) __bf16 bf8;
typedef __attribute__((ext_vector_type(4))) float f4v;

#define GLB(p) ((const __attribute__((address_space(1))) void*)(p))
#define LDS(p) ((__attribute__((address_space(3))) void*)(p))

static __device__ __forceinline__ float b2f(u16 u) {
    union { unsigned int i; float f; } v; v.i = ((unsigned int)u) << 16; return v.f;
}
static __device__ __forceinline__ u16 f2b(float f) {
    union { float f; unsigned int i; } v; v.f = f;
    v.i += 0x7fffu + ((v.i >> 16) & 1u);   // RNE
    return (u16)(v.i >> 16);
}

// ---------------- fused f32 -> bf16 convert (X, W_qkv, W_o) ----------------
__global__ __launch_bounds__(256) void k_conv(const float* __restrict__ X,
                                              const float* __restrict__ Wq,
                                              const float* __restrict__ Wo,
                                              u16* __restrict__ Xb,
                                              u16* __restrict__ Wqb,
                                              u16* __restrict__ Wob) {
    int i = blockIdx.x * 256 + threadIdx.x;      // 8388608 quads total
    const float* in; u16* out; int off;
    if (i < 4194304)      { in = X;  out = Xb;  off = i; }
    else if (i < 7340032) { in = Wq; out = Wqb; off = i - 4194304; }
    else                  { in = Wo; out = Wob; off = i - 7340032; }
    float4 v = ((const float4*)in)[off];
    union { u16 u[4]; unsigned long long ll; } o;
    o.u[0] = f2b(v.x); o.u[1] = f2b(v.y); o.u[2] = f2b(v.z); o.u[3] = f2b(v.w);
    ((unsigned long long*)out)[off] = o.ll;
}

// ============ C = A(MxK) * B(NxK)^T, 256x256 tile, BK=64, 8 waves ============
// Round-8 proven core (200us, 46.5% MfmaUtil): ONE barrier per phase (at MFMA
// start); burst-stage next K-tile at p0; vmcnt(0) only at p3 (loads aged 3
// phases). 128B rows, 8-granule XOR swizzle g^(row&7); inverse on staging src.
// MODE 0: padded-LDS-transpose epilogue -> Q/K [bh][t][128] WITH FUSED ROPE,
//         V transposed [bh][128][t].   MODE 1: f32 row-major C.
template<int MODE>
__global__ __launch_bounds__(512, 2) void k_gemm_bt(
    const u16* __restrict__ A, const u16* __restrict__ B,
    int K, int N, int gx,
    u16* __restrict__ Qb, u16* __restrict__ Kb, u16* __restrict__ Vt,
    float* __restrict__ Cf, const int* __restrict__ pos)
{
    extern __shared__ __align__(16) u16 Ls[];   // 2 dbufs x 64KB; epilogue 256x264

    const int t    = threadIdx.x;
    const int lane = t & 63;
    const int wid  = t >> 6;
    const int wm = wid >> 2, wn = wid & 3;       // 2x4 wave grid; per-wave 128x64 out
    const int la = lane & 15, lb = lane >> 4;

    // XCD-bijective block swizzle (grid % 8 == 0)
    const int bid = (int)blockIdx.x;
    const int id2 = (bid & 7) * ((int)gridDim.x >> 3) + (bid >> 3);
    const int bx = id2 % gx, by = id2 / gx;
    const long arow0 = (long)by * 256;
    const long brow0 = (long)bx * 256;

    // staging: linear LDS dest, inverse-swizzled global source
    const int sr = t >> 3;                       // row in half (0..63); +64 for 2nd inst
    const int sg = (t & 7) ^ (sr & 7);           // global k-granule (16B)
    const u16* Asrc = A + (arow0 + sr) * (long)K + sg * 8;
    const u16* Bsrc = B + (brow0 + sr) * (long)K + sg * 8;
    const long K64 = 64 * (long)K, K128 = 128 * (long)K;
    u16* ldst = Ls + t * 8;

#define STG(q_, op_, h_, kt_) do {                                              \
        const u16* s_ = ((op_) ? Bsrc : Asrc) + (h_) * K128 + (long)(kt_) * 64; \
        u16* d_ = ldst + (q_) * 32768 + (op_) * 16384 + (h_) * 8192;            \
        __builtin_amdgcn_global_load_lds(GLB(s_),       LDS(d_),        16, 0, 0); \
        __builtin_amdgcn_global_load_lds(GLB(s_ + K64), LDS(d_ + 4096), 16, 0, 0); \
    } while (0)
#define RD(off) (*(const bf8*)(Ls + (off)))

    f4v acc[8][4];
#pragma unroll
    for (int m = 0; m < 8; m++)
#pragma unroll
        for (int n = 0; n < 4; n++) acc[m][n] = (f4v){0.f, 0.f, 0.f, 0.f};

    // fragment-read swizzled offsets (u16 units)
    const int r7 = la & 7;
    const int gA0 = (lb ^ r7) * 8;               // ks=0 (granules 0..3)
    const int gA1 = ((lb ^ r7) ^ 4) * 8;         // ks=1 (granules 4..7)
    const int aRow = wm * 8192 + la * 64;                                   // + mi*1024
    const int bRow = 16384 + (wn >> 1) * 8192 + ((wn & 1) * 64 + la) * 64;  // + ni*1024

    const int NKT = K >> 6;
    STG(0, 0, 0, 0); STG(0, 0, 1, 0); STG(0, 1, 0, 0); STG(0, 1, 1, 0);
    asm volatile("s_waitcnt vmcnt(0)" ::: "memory");
    __builtin_amdgcn_s_barrier();

    for (int X = 0; X < NKT; ++X) {
        const int D = (X & 1) << 15;
        const int q = (X + 1) & 1;
        const int S = (X + 1 < NKT) ? X + 1 : NKT - 1;
        bf8 aR[4][2], b0[2][2], b1[2][2];

        // p0: A-sub0 + B-sub0 reads, burst-stage tile X+1 | bar | MFMA Q(0,0)
#pragma unroll
        for (int mi = 0; mi < 4; mi++) {
            aR[mi][0] = RD(D + aRow + mi * 1024 + gA0);
            aR[mi][1] = RD(D + aRow + mi * 1024 + gA1);
        }
#pragma unroll
        for (int nl = 0; nl < 2; nl++) {
            b0[nl][0] = RD(D + bRow + nl * 1024 + gA0);
            b0[nl][1] = RD(D + bRow + nl * 1024 + gA1);
        }
        STG(q, 0, 0, S); STG(q, 0, 1, S); STG(q, 1, 0, S); STG(q, 1, 1, S);
        __builtin_amdgcn_s_barrier();
        __builtin_amdgcn_s_setprio(1);
#pragma unroll
        for (int mi = 0; mi < 4; mi++)
#pragma unroll
            for (int nl = 0; nl < 2; nl++) {
                acc[mi][nl] = __builtin_amdgcn_mfma_f32_16x16x32_bf16(aR[mi][0], b0[nl][0], acc[mi][nl], 0, 0, 0);
                acc[mi][nl] = __builtin_amdgcn_mfma_f32_16x16x32_bf16(aR[mi][1], b0[nl][1], acc[mi][nl], 0, 0, 0);
            }
        __builtin_amdgcn_s_setprio(0);

        // p1: B-sub1 reads | bar | MFMA Q(0,1)
#pragma unroll
        for (int nl = 0; nl < 2; nl++) {
            b1[nl][0] = RD(D + bRow + (2 + nl) * 1024 + gA0);
            b1[nl][1] = RD(D + bRow + (2 + nl) * 1024 + gA1);
        }
        __builtin_amdgcn_s_barrier();
        __builtin_amdgcn_s_setprio(1);
#pragma unroll
        for (int mi = 0; mi < 4; mi++)
#pragma unroll
            for (int nl = 0; nl < 2; nl++) {
                acc[mi][2 + nl] = __builtin_amdgcn_mfma_f32_16x16x32_bf16(aR[mi][0], b1[nl][0], acc[mi][2 + nl], 0, 0, 0);
                acc[mi][2 + nl] = __builtin_amdgcn_mfma_f32_16x16x32_bf16(aR[mi][1], b1[nl][1], acc[mi][2 + nl], 0, 0, 0);
            }
        __builtin_amdgcn_s_setprio(0);

        // p2: A-sub1 reads | bar | MFMA Q(1,1)
#pragma unroll
        for (int mi = 0; mi < 4; mi++) {
            aR[mi][0] = RD(D + aRow + (4 + mi) * 1024 + gA0);
            aR[mi][1] = RD(D + aRow + (4 + mi) * 1024 + gA1);
        }
        __builtin_amdgcn_s_barrier();
        __builtin_amdgcn_s_setprio(1);
#pragma unroll
        for (int mi = 0; mi < 4; mi++)
#pragma unroll
            for (int nl = 0; nl < 2; nl++) {
                acc[4 + mi][2 + nl] = __builtin_amdgcn_mfma_f32_16x16x32_bf16(aR[mi][0], b1[nl][0], acc[4 + mi][2 + nl], 0, 0, 0);
                acc[4 + mi][2 + nl] = __builtin_amdgcn_mfma_f32_16x16x32_bf16(aR[mi][1], b1[nl][1], acc[4 + mi][2 + nl], 0, 0, 0);
            }
        __builtin_amdgcn_s_setprio(0);

        // p3: drain staging (aged 3 phases, ~free) | bar | MFMA Q(1,0)
        asm volatile("s_waitcnt vmcnt(0)" ::: "memory");
        __builtin_amdgcn_s_barrier();
        __builtin_amdgcn_s_setprio(1);
#pragma unroll
        for (int mi = 0; mi < 4; mi++)
#pragma unroll
            for (int nl = 0; nl < 2; nl++) {
                acc[4 + mi][nl] = __builtin_amdgcn_mfma_f32_16x16x32_bf16(aR[mi][0], b0[nl][0], acc[4 + mi][nl], 0, 0, 0);
                acc[4 + mi][nl] = __builtin_amdgcn_mfma_f32_16x16x32_bf16(aR[mi][1], b0[nl][1], acc[4 + mi][nl], 0, 0, 0);
            }
        __builtin_amdgcn_s_setprio(0);
    }
#undef STG
#undef RD

    if (MODE == 1) {
#pragma unroll
        for (int mi = 0; mi < 8; mi++)
#pragma unroll
            for (int ni = 0; ni < 4; ni++) {
                const long grow0 = arow0 + wm * 128 + mi * 16 + lb * 4;
                const int  gcol  = (int)brow0 + wn * 64 + ni * 16 + la;
#pragma unroll
                for (int i = 0; i < 4; i++)
                    Cf[(grow0 + i) * (long)N + gcol] = acc[mi][ni][i];
            }
        return;
    }

    // ---- MODE 0 epilogue: transpose through padded LDS, coalesced stores ----
    __syncthreads();                 // K-loop done; reuse Ls as E[.. * 264]
    const int part = (int)(brow0 >> 11);         // 0=Q 1=K 2=V
    const int colp = (int)brow0 & 2047;
    const int h0   = colp >> 7;                  // first head in tile (2 heads/tile)
    const int bidx = (int)(arow0 >> 11);
    const int t0   = (int)arow0 & 2047;

    if (part == 2) {
        // E[dl*264 + tl]
#pragma unroll
        for (int mi = 0; mi < 8; mi++)
#pragma unroll
            for (int ni = 0; ni < 4; ni++) {
                const int tlb = wm * 128 + mi * 16 + lb * 4;
                const int dl  = wn * 64 + ni * 16 + la;
#pragma unroll
                for (int i2 = 0; i2 < 2; i2++) {
                    unsigned int pk = (unsigned int)f2b(acc[mi][ni][i2 * 2])
                                    | ((unsigned int)f2b(acc[mi][ni][i2 * 2 + 1]) << 16);
                    *(unsigned int*)(Ls + dl * 264 + tlb + i2 * 2) = pk;
                }
            }
        __syncthreads();
#pragma unroll
        for (int j = 0; j < 16; j++) {
            const int dl = j * 16 + wid * 2 + (lane >> 5);
            const int c  = lane & 31;
            bf8 v = *(const bf8*)(Ls + dl * 264 + c * 8);
            const long bh = (long)(bidx * 16 + h0 + (dl >> 7));
            *(bf8*)(Vt + (bh << 18) + ((long)(dl & 127) << 11) + t0 + c * 8) = v;
        }
    } else {
        u16* dst = (part == 0) ? Qb : Kb;
        // E[tl*264 + dl]
#pragma unroll
        for (int mi = 0; mi < 8; mi++)
#pragma unroll
            for (int ni = 0; ni < 4; ni++) {
                const int tlb = wm * 128 + mi * 16 + lb * 4;
                const int dl  = wn * 64 + ni * 16 + la;
#pragma unroll
                for (int i = 0; i < 4; i++)
                    Ls[(tlb + i) * 264 + dl] = f2b(acc[mi][ni][i]);
            }
        __syncthreads();
        // fused RoPE: within-head d = c*8..c*8+7, pairs j = c*4+p
        const int c = t & 15;
        float invf[4];
#pragma unroll
        for (int p2 = 0; p2 < 4; p2++)
            invf[p2] = exp2f((float)(c * 4 + p2) * -0.20762050593046014f);
#pragma unroll
        for (int j = 0; j < 16; j++) {
            const int R  = j * 32 + (t >> 4);
            const int tl = R >> 1, hh = R & 1;
            s8v v = *(const s8v*)(Ls + tl * 264 + hh * 128 + c * 8);
            const float pf = (float)pos[t0 + tl];
            union { u16 u[8]; s8v v; } ov;
#pragma unroll
            for (int p2 = 0; p2 < 4; p2++) {
                float x1 = b2f((u16)v[2 * p2]);
                float x2 = b2f((u16)v[2 * p2 + 1]);
                float sn, cs;
                __sincosf(pf * invf[p2], &sn, &cs);
                ov.u[2 * p2]     = f2b(x1 * cs - x2 * sn);
                ov.u[2 * p2 + 1] = f2b(x1 * sn + x2 * cs);
            }
            const long bh = (long)(bidx * 16 + h0 + hh);
            *(s8v*)(dst + ((bh << 11) + t0 + tl) * 128 + c * 8) = ov.v;
        }
    }
}

// ---------------- causal flash attention ----------------
// 256 threads = 4 waves (1 wave/SIMD) -> 2 independent blocks/CU (72KB LDS).
// KVBLK=64 double-buffered; raw s_barrier + vmcnt(0) on a stage aged one FULL
// iteration (never drains the fresh stage). Softmax/PV per 32-half (P-LDS reuse).
__global__ __launch_bounds__(256) void k_attn(const u16* __restrict__ Qb,
                                              const u16* __restrict__ Kb,
                                              const u16* __restrict__ Vt,
                                              u16* __restrict__ Ob)
{
    extern __shared__ __align__(16) u16 Sm[];
    u16* KsD = Sm;                    // [2][64*128]  32KB (256B rows, 16 granules)
    u16* VsD = Sm + 16384;            // [2][128*64]  32KB (128B rows, 8 granules)
    u16* PlD = Sm + 32768;            // [4][1024]     8KB per-wave P buffers

    const int tid  = threadIdx.x;
    const int lane = tid & 63;
    const int w    = tid >> 6;                      // 0..3
    const int la = lane & 15, lb = lane >> 4;
    const int qg = 15 - ((int)blockIdx.x >> 6);     // LPT: longest first
    const int bh = blockIdx.x & 63;
    const long base = (long)bh << 18;               // bh * 2048 * 128
    const int qt = qg * 4 + w;                      // 32-row q tile
    const int q0 = qt * 32;
    const int n32 = qt + 1;                         // valid 32-wide kv tiles
    const int NT = qg * 2 + 2;                      // 64-wide kv tiles in block
    const float scale = 0.08838834764831845f;

    bf8 qf[2][4];
#pragma unroll
    for (int m = 0; m < 2; m++)
#pragma unroll
        for (int kb = 0; kb < 4; kb++)
            qf[m][kb] = *(const bf8*)(Qb + base + (long)(q0 + m * 16 + la) * 128 + kb * 32 + lb * 8);

    f4v o[2][8];
#pragma unroll
    for (int m = 0; m < 2; m++)
#pragma unroll
        for (int n = 0; n < 8; n++) o[m][n] = (f4v){0.f, 0.f, 0.f, 0.f};
    float lst[2][4];
#pragma unroll
    for (int m = 0; m < 2; m++)
#pragma unroll
        for (int i = 0; i < 4; i++) lst[m][i] = 0.f;

    char* Pb = (char*)(PlD + w * 1024);

    // staging geometry (inverse-swizzled global source, linear LDS dest)
    const int krow = tid >> 4;                      // 0..15 (+16i)
    const int kgr  = (tid & 15) ^ (krow & 7);       // K granule (16 per 256B row)
    const int vrow = tid >> 3;                      // 0..31 (+32i)
    const int vgr  = (tid & 7) ^ (vrow & 7);        // V granule (8 per 128B row)

#define STAGE(buf, jt_) do {                                                         \
        const int kv0_ = (jt_) * 64;                                                \
        _Pragma("unroll")                                                           \
        for (int i_ = 0; i_ < 4; i_++) {                                            \
            __builtin_amdgcn_global_load_lds(                                       \
                GLB(Kb + base + (long)(kv0_ + i_ * 16 + krow) * 128 + kgr * 8),     \
                LDS(KsD + (buf) * 8192 + i_ * 2048 + tid * 8), 16, 0, 0);           \
            __builtin_amdgcn_global_load_lds(                                       \
                GLB(Vt + base + (long)(i_ * 32 + vrow) * 2048 + kv0_ + vgr * 8),    \
                LDS(VsD + (buf) * 8192 + i_ * 2048 + tid * 8), 16, 0, 0);           \
        }                                                                           \
    } while (0)

    STAGE(0, 0);

    for (int jt = 0; jt < NT; ++jt) {
        const int buf = jt & 1;
        // stage(jt) was issued one full iteration ago -> this wait is ~free
        asm volatile("s_waitcnt vmcnt(0)" ::: "memory");
        __builtin_amdgcn_s_barrier();
        if (jt + 1 < NT) STAGE(buf ^ 1, jt + 1);

        const u16* KsB = KsD + buf * 8192;
        const u16* VsB = VsD + buf * 8192;

#pragma unroll
        for (int h = 0; h < 2; h++) {
            const int j32 = jt * 2 + h;
            if (j32 < n32) {
                // QK^T (swizzled reads from Ks)
                f4v s[2][2];
                s[0][0] = s[0][1] = s[1][0] = s[1][1] = (f4v){0.f, 0.f, 0.f, 0.f};
#pragma unroll
                for (int n = 0; n < 2; n++) {
                    const int rr = h * 32 + n * 16 + la;
#pragma unroll
                    for (int kb = 0; kb < 4; kb++) {
                        bf8 kf = *(const bf8*)(KsB + rr * 128 + (((kb * 4 + lb) ^ (la & 7)) * 8));
                        s[0][n] = __builtin_amdgcn_mfma_f32_16x16x32_bf16(qf[0][kb], kf, s[0][n], 0, 0, 0);
                        s[1][n] = __builtin_amdgcn_mfma_f32_16x16x32_bf16(qf[1][kb], kf, s[1][n], 0, 0, 0);
                    }
                }

                // V fragments (swizzled reads from Vs)
                bf8 vf[8];
#pragma unroll
                for (int nO = 0; nO < 8; nO++) {
                    const int rv = nO * 16 + la;
                    vf[nO] = *(const bf8*)(VsB + rv * 64 + (((h * 4 + lb) ^ (la & 7)) * 8));
                }

                const bool diag = (j32 == qt);
                float p[2][2][4];
#pragma unroll
                for (int m = 0; m < 2; m++)
#pragma unroll
                    for (int n = 0; n < 2; n++)
#pragma unroll
                        for (int i = 0; i < 4; i++) {
                            float v = __expf(fmaf(s[m][n][i], scale, -8.0f));
                            if (diag && (n * 16 + la) > (m * 16 + lb * 4 + i)) v = 0.f;
                            p[m][n][i] = v;
                            lst[m][i] += v;
                        }

                // P -> per-wave LDS (swizzled), re-fragment as MFMA A-operand
#pragma unroll
                for (int m = 0; m < 2; m++)
#pragma unroll
                    for (int n = 0; n < 2; n++)
#pragma unroll
                        for (int i = 0; i < 4; i++) {
                            const int row = m * 16 + lb * 4 + i;
                            const int colb = (n * 16 + la) * 2;
                            *(u16*)(Pb + row * 64 + (colb ^ ((row & 3) << 4))) = f2b(p[m][n][i]);
                        }
                bf8 pa[2];
#pragma unroll
                for (int am = 0; am < 2; am++) {
                    const int row = am * 16 + la;
                    pa[am] = *(const bf8*)(Pb + row * 64 + ((lb * 16) ^ ((row & 3) << 4)));
                }
#pragma unroll
                for (int nO = 0; nO < 8; nO++) {
                    o[0][nO] = __builtin_amdgcn_mfma_f32_16x16x32_bf16(pa[0], vf[nO], o[0][nO], 0, 0, 0);
                    o[1][nO] = __builtin_amdgcn_mfma_f32_16x16x32_bf16(pa[1], vf[nO], o[1][nO], 0, 0, 0);
                }
            }
        }
        // all ds_reads of buf were consumed by MFMAs above -> bare barrier is safe
        __builtin_amdgcn_s_barrier();
    }
#undef STAGE

    float linv[2][4];
#pragma unroll
    for (int m = 0; m < 2; m++)
#pragma unroll
        for (int i = 0; i < 4; i++) {
            float l = lst[m][i];
            l += __shfl_xor(l, 1);
            l += __shfl_xor(l, 2);
            l += __shfl_xor(l, 4);
            l += __shfl_xor(l, 8);
            linv[m][i] = 1.0f / l;
        }

    const int b = bh >> 4, h = bh & 15;
#pragma unroll
    for (int m = 0; m < 2; m++)
#pragma unroll
        for (int nO = 0; nO < 8; nO++)
#pragma unroll
            for (int i = 0; i < 4; i++) {
                const int row = q0 + m * 16 + lb * 4 + i;
                const int d = nO * 16 + la;
                Ob[((long)(b * 2048 + row) << 11) + h * 128 + d] = f2b(o[m][nO][i] * linv[m][i]);
            }
}

extern "C" void kernel_launch(void* const* d_in, const int* in_sizes, int n_in,
                              void* d_out, int out_size, void* d_ws, size_t ws_size,
                              hipStream_t stream)
{
    const float* X    = (const float*)d_in[0];
    const int*   pos  = (const int*)d_in[1];
    const float* Wqkv = (const float*)d_in[2];
    const float* Wo   = (const float*)d_in[3];
    float* out = (float*)d_out;

    char* ws = (char*)d_ws;
    u16* Xb    = (u16*)(ws + 0);          // 8192x2048 bf16   (32 MiB)
    u16* Wqkvb = (u16*)(ws + 33554432);   // 6144x2048 bf16   (24 MiB)
    u16* Wob   = (u16*)(ws + 58720256);   // 2048x2048 bf16   ( 8 MiB)
    u16* Qb    = (u16*)(ws + 67108864);   // [bh][t][128] bf16 (32 MiB)
    u16* Kb    = (u16*)(ws + 100663296);  // [bh][t][128]
    u16* Vt    = (u16*)(ws + 134217728);  // [bh][128][t]  (transposed)
    u16* Ob    = (u16*)(ws + 167772160);  // [b][t][2048] bf16

    k_conv<<<32768, 256, 0, stream>>>(X, Wqkv, Wo, Xb, Wqkvb, Wob);
    // GEMM1: M=8192 N=6144 K=2048 -> grid 24x32 = 768 blocks (RoPE fused)
    k_gemm_bt<0><<<768, 512, 135168, stream>>>(Xb, Wqkvb, 2048, 6144, 24, Qb, Kb, Vt, nullptr, pos);
    // attn: 64 bh x 16 q-groups = 1024 blocks, 256 thr, 72KB LDS (2 blocks/CU)
    k_attn<<<1024, 256, 73728, stream>>>(Qb, Kb, Vt, Ob);
    // GEMM2: M=8192 N=2048 K=2048 -> grid 8x32 = 256 blocks
    k_gemm_bt<1><<<256, 512, 131072, stream>>>(Ob, Wob, 2048, 2048, 8, nullptr, nullptr, nullptr, out, nullptr);
}